// Round 8
// baseline (752.998 us; speedup 1.0000x reference)
//
#include <hip/hip_runtime.h>
#include <math.h>

#define B_    16384
#define N_    1152
#define KPAD  2560   // 1152 + 576 + 576 + 144 (cv23 3-slot) + 112 pad -> 80 x 32
#define NKT   80
#define KLOOP 256    // per-j2: 72 slots + 56 pad -> 128, x2
#define NOUT  4608
#define NT2   18     // NOUT/256
#define LOG2F_ 0.69314718055994530942f

typedef unsigned short ushort_t;
typedef __attribute__((ext_vector_type(8))) short short8;
typedef __attribute__((ext_vector_type(16))) float floatx16;

__device__ __forceinline__ float log_cosh_f(float t) {
    float a = fabsf(t);
    return a + __logf(1.0f + __expf(-2.0f * a)) - LOG2F_;
}
__device__ __forceinline__ ushort_t bf16_rne(float f) {
    unsigned int u = __float_as_uint(f);
    return (ushort_t)((u + 0x7fffu + ((u >> 16) & 1u)) >> 16);
}
__device__ __forceinline__ float bf16_to_f(ushort_t h) {
    return __uint_as_float(((unsigned int)h) << 16);
}

typedef __attribute__((address_space(1))) const unsigned int guint;
typedef __attribute__((address_space(3))) unsigned int luint;
__device__ __forceinline__ void gload16(const ushort_t* src, ushort_t* dst) {
    __builtin_amdgcn_global_load_lds((guint*)src, (luint*)dst, 16, 0, 0);
}

// ---------------------------------------------------------------------------
// Kernel 1: gather + transpose + bf16-encode weights (KPAD=2560; >=2448 zero).
// ---------------------------------------------------------------------------
__global__ __launch_bounds__(256) void build_w(
    const int* __restrict__ symm,
    const int* __restrict__ c0s, const int* __restrict__ c1s,
    const int* __restrict__ c2s, const int* __restrict__ c3s,
    const float* __restrict__ sk,
    const float* __restrict__ ck0, const float* __restrict__ ck1,
    const float* __restrict__ ck2, const float* __restrict__ ck3,
    const float* __restrict__ l0k, const float* __restrict__ l1k,
    ushort_t* __restrict__ Wb, ushort_t* __restrict__ LWb)
{
    __shared__ int idx[2352];
    const int s = blockIdx.x;
    const int tid = threadIdx.x;
    for (int i = tid; i < 1152; i += 256) idx[i] = symm[s * N_ + i];
    for (int i = tid; i < 576; i += 256) idx[1152 + i] = c0s[s * 576 + i];
    for (int i = tid; i < 576; i += 256) idx[1728 + i] = c1s[s * 576 + i];
    if (tid < 24) idx[2304 + tid] = c2s[s * 24 + tid];
    else if (tid < 48) idx[2328 + (tid - 24)] = c3s[s * 24 + (tid - 24)];
    __syncthreads();
    for (int f = 0; f < 8; ++f) {
        ushort_t* wr = Wb + (size_t)(s * 8 + f) * KPAD;
        for (int k = tid; k < KPAD; k += 256) {
            ushort_t o;
            if (k < 1152)      o = bf16_rne(sk[f * N_ + idx[k]]);
            else if (k < 1728) o = bf16_rne(ck0[f * 576 + idx[k]]);
            else if (k < 2304) o = bf16_rne(ck1[f * 576 + idx[k]]);
            else if (k < 2448) {
                int q = k - 2304, g = q / 48, c = q - g * 48;
                float w = (c < 24) ? ck2[f * 24 + idx[2304 + c]]
                                   : ck3[f * 24 + idx[2328 + (c - 24)]];
                ushort_t hi = bf16_rne(w);
                o = (g < 2) ? hi : bf16_rne(w - bf16_to_f(hi));
            } else o = 0;
            wr[k] = o;
        }
        ushort_t* lr = LWb + (size_t)(s * 8 + f) * KLOOP;
        for (int k2 = tid; k2 < KLOOP; k2 += 256) {
            int j2 = k2 >> 7, q = k2 & 127;
            ushort_t o = 0;
            if (q < 72) {
                int g = q / 24, c = q - g * 24;
                float w = j2 ? l1k[f * 24 + idx[2328 + c]]
                             : l0k[f * 24 + idx[2304 + c]];
                ushort_t hi = bf16_rne(w);
                o = (g < 2) ? hi : bf16_rne(w - bf16_to_f(hi));
            }
            lr[k2] = o;
        }
    }
}

// ---------------------------------------------------------------------------
// Kernel 2: augmented A matrix (bf16) + loop-cv matrix + scalar bias.
// ---------------------------------------------------------------------------
__global__ __launch_bounds__(256) void build_cv(
    const float* __restrict__ x,
    const int* __restrict__ corr0, const int* __restrict__ corr1,
    const int* __restrict__ corr2, const int* __restrict__ corr3,
    const float* __restrict__ vb,
    const float* __restrict__ cb0, const float* __restrict__ cb1,
    const float* __restrict__ cb2, const float* __restrict__ cb3,
    ushort_t* __restrict__ XA, ushort_t* __restrict__ CVL,
    float* __restrict__ initb)
{
    __shared__ float xs[N_];
    __shared__ float red[256];
    __shared__ float cvhi[48], cvlo[48];
    const int tid = threadIdx.x;
    const int b = blockIdx.x;
    ushort_t* xr = XA + (size_t)b * KPAD;

    float bias = 0.f;
    const float vb0 = vb[0], vb1 = vb[1];
    for (int i = tid; i < N_; i += 256) {
        float v = x[(size_t)b * N_ + i];
        xs[i] = v;
        bias += v * ((i & 1) ? vb1 : vb0);
        xr[i] = bf16_rne(v);
    }
    __syncthreads();
    float s0 = 0.f, s1 = 0.f, s2 = 0.f, s3 = 0.f;
    for (int c = tid; c < 576; c += 256) {
        const int* i0 = corr0 + c * 4;
        float p = xs[i0[0]] * xs[i0[1]] * xs[i0[2]] * xs[i0[3]];
        xr[1152 + c] = bf16_rne(p); s0 += p;
        const int* i1 = corr1 + c * 4;
        float q = xs[i1[0]] * xs[i1[1]] * xs[i1[2]] * xs[i1[3]];
        xr[1728 + c] = bf16_rne(q); s1 += q;
    }
    if (tid < 48) {
        int j2 = tid / 24, c = tid - j2 * 24;
        const int* ii = (j2 ? corr3 : corr2) + c * 24;
        float p = 1.f;
        for (int j = 0; j < 24; ++j) p *= xs[ii[j]];
        float hv = bf16_to_f(bf16_rne(p));
        cvhi[tid] = hv;
        cvlo[tid] = p - hv;
        if (j2) s3 = p; else s2 = p;
    }
    __syncthreads();
    for (int i = tid; i < KPAD - 2304; i += 256) {
        ushort_t o = 0;
        if (i < 144) {
            int g = i / 48, c = i - g * 48;
            o = bf16_rne(g == 1 ? cvlo[c] : cvhi[c]);
        }
        xr[2304 + i] = o;
    }
    ushort_t* cr = CVL + (size_t)b * KLOOP;
    for (int k2 = tid; k2 < KLOOP; k2 += 256) {
        int j2 = k2 >> 7, q = k2 & 127;
        ushort_t o = 0;
        if (q < 72) {
            int g = q / 24, c = q - g * 24;
            o = bf16_rne(g == 1 ? cvlo[j2 * 24 + c] : cvhi[j2 * 24 + c]);
        }
        cr[k2] = o;
    }
    bias += cb0[0] * s0 + cb1[0] * s1 + cb2[0] * s2 + cb3[0] * s3;
    red[tid] = bias;
    __syncthreads();
    for (int off = 128; off; off >>= 1) {
        if (tid < off) red[tid] += red[tid + off];
        __syncthreads();
    }
    if (tid == 0) initb[b] = red[0];
}

// ---------------------------------------------------------------------------
// Kernel 3: 256x256 MFMA GEMM, 32x32x16 bf16, 8 waves (2M x 4N), per-wave
// 128x64 (acc 4x2 floatx16 = 128 VGPR), BK=32, 4 LDS buffers (128 KB).
// REGISTER READ-AHEAD PIPELINE (the structural fix for the 33% plateau):
//   per tile t: {read frags(t,ks1)->Y || stage(t+3)} ; MFMA(t,ks0 from X) ;
//   vmcnt(8)+lgkmcnt(0) ; barrier ; read frags(t+1,ks0)->X ; MFMA(t,ks1 from Y)
// ds_reads always issued one MFMA-phase before use -> LDS and matrix pipes
// overlap within each wave. vmcnt(8): tiles t+2,t+3 stay in flight (4 loads
// each); t+1 proven resident at the barrier. Swizzle: phys_oct = logical_oct
// ^ ((row>>1)&3), both sides (rounds 5-7 verified, 0 conflicts; balanced for
// the 32-row frag reads too: class (4r+o)%8 covers all 8 per 8-lane group).
// ---------------------------------------------------------------------------
__global__ __launch_bounds__(512, 2) void mfma_gemm(
    const ushort_t* __restrict__ XA, const ushort_t* __restrict__ Wb,
    const ushort_t* __restrict__ CVL, const ushort_t* __restrict__ LWb,
    const float* __restrict__ hidden_bias,
    const float* __restrict__ l0hb, const float* __restrict__ l1hb,
    float* __restrict__ partials)
{
    __shared__ __align__(16) ushort_t sh[65536];  // 4 bufs x (A 8192 | B 8192)
    __shared__ float redsh[1280];                 // [256 rows][5]

    const int tid = threadIdx.x;
    const int l = tid & 63, w = tid >> 6;
    const int wm = w >> 2, wn = w & 3;            // 2 M-waves x 4 N-waves
    const int l31 = l & 31, lh = l >> 5;
    const int srow = l >> 2;
    const int sgr8 = ((l & 3) ^ ((srow >> 1) & 3)) * 8;   // stage src swizzle

    // bijective XCD swizzle: 1152 blocks = 8 chunks x 144, nt-fastest
    const int bid = blockIdx.x;
    const int swz = (bid & 7) * 144 + (bid >> 3);
    const int nt = swz % NT2, bt = swz / NT2;     // bt 0..63
    const int n0 = nt * 256, b0 = bt * 256;

    const ushort_t* XAb  = XA  + (size_t)b0 * KPAD;
    const ushort_t* Wbb  = Wb  + (size_t)n0 * KPAD;
    const ushort_t* CVb  = CVL + (size_t)b0 * KLOOP;
    const ushort_t* LWbb = LWb + (size_t)n0 * KLOOP;

    // frag read addressing: A row = wm*128 + mi*32 + l31, oct = (2ks+lh)^f
    const int fsw = (l31 >> 1) & 3;
    const int ao0 = l31 * 32 + (((0 + lh) ^ fsw) * 8);    // ks=0
    const int ao1 = l31 * 32 + (((2 + lh) ^ fsw) * 8);    // ks=1
    const int aBase = wm * 4096;                  // wm*128 rows * 32
    const int bBase = 8192 + wn * 2048;           // B region + wn*64 rows * 32

    floatx16 acc[4][2];
    short8 aX[4], bX[2], aY[4], bY[2];

    auto STGA = [&](const ushort_t* g, int stride, int kg, int bufbase) {
#pragma unroll
        for (int i = 0; i < 2; ++i) {
            const int r0 = i * 128 + w * 16;
            gload16(g + (size_t)(r0 + srow) * stride + kg + sgr8,
                    &sh[bufbase + r0 * 32]);
        }
    };
    auto STAGE = [&](int kg, int bufbase) {
        STGA(XAb, KPAD, kg, bufbase);
        STGA(Wbb, KPAD, kg, bufbase + 8192);
    };
    auto RD = [&](int bufbase, int ao, short8* a, short8* b) {
#pragma unroll
        for (int mi = 0; mi < 4; ++mi)
            a[mi] = *(const short8*)&sh[bufbase + aBase + mi * 1024 + ao];
#pragma unroll
        for (int ni = 0; ni < 2; ++ni)
            b[ni] = *(const short8*)&sh[bufbase + bBase + ni * 1024 + ao];
    };
    auto MM = [&](short8* a, short8* b) {
        __builtin_amdgcn_s_setprio(1);
#pragma unroll
        for (int mi = 0; mi < 4; ++mi)
#pragma unroll
            for (int ni = 0; ni < 2; ++ni)
                acc[mi][ni] = __builtin_amdgcn_mfma_f32_32x32x16_bf16(
                    a[mi], b[ni], acc[mi][ni], 0, 0, 0);
        __builtin_amdgcn_s_setprio(0);
    };
    auto ZACC = [&]() {
#pragma unroll
        for (int mi = 0; mi < 4; ++mi)
#pragma unroll
            for (int ni = 0; ni < 2; ++ni)
#pragma unroll
                for (int r = 0; r < 16; ++r) acc[mi][ni][r] = 0.f;
    };

    ZACC();

    // ---- prologue: stage tiles 0..2; tile0 resident; preload frags(0,ks0) --
    STAGE(0, 0); STAGE(32, 16384); STAGE(64, 32768);
    asm volatile("s_waitcnt vmcnt(8)" ::: "memory");
    __builtin_amdgcn_sched_barrier(0);
    __builtin_amdgcn_s_barrier();
    RD(0, ao0, aX, bX);

    // ---- main loop: t = 0..75 (19 x 4, static buffers) ----
#pragma unroll 1
    for (int tb = 0; tb < 19; ++tb) {
#pragma unroll
        for (int ph = 0; ph < 4; ++ph) {
            const int t = tb * 4 + ph;
            const int cb = ph * 16384;
            const int nb = ((ph + 3) & 3) * 16384;
            const int b1 = ((ph + 1) & 3) * 16384;
            RD(cb, ao1, aY, bY);                  // frags(t, ks1)
            STAGE((t + 3) * 32, nb);              // stage tile t+3
            MM(aX, bX);                           // MFMA(t, ks0)
            asm volatile("s_waitcnt vmcnt(8) lgkmcnt(0)" ::: "memory");
            __builtin_amdgcn_sched_barrier(0);
            __builtin_amdgcn_s_barrier();         // t+1 resident everywhere
            RD(b1, ao0, aX, bX);                  // frags(t+1, ks0)
            MM(aY, bY);                           // MFMA(t, ks1)
        }
    }
    // ---- peeled tail t = 76..79 ----
    RD(0, ao1, aY, bY); STAGE(79 * 32, 49152); MM(aX, bX);        // t=76 (buf0)
    asm volatile("s_waitcnt vmcnt(8) lgkmcnt(0)" ::: "memory");
    __builtin_amdgcn_sched_barrier(0); __builtin_amdgcn_s_barrier();
    RD(16384, ao0, aX, bX); MM(aY, bY);
    RD(16384, ao1, aY, bY); MM(aX, bX);                           // t=77 (buf1)
    asm volatile("s_waitcnt vmcnt(4) lgkmcnt(0)" ::: "memory");
    __builtin_amdgcn_sched_barrier(0); __builtin_amdgcn_s_barrier();
    RD(32768, ao0, aX, bX); MM(aY, bY);
    RD(32768, ao1, aY, bY); MM(aX, bX);                           // t=78 (buf2)
    asm volatile("s_waitcnt vmcnt(0) lgkmcnt(0)" ::: "memory");
    __builtin_amdgcn_sched_barrier(0); __builtin_amdgcn_s_barrier();
    RD(49152, ao0, aX, bX); MM(aY, bY);
    RD(49152, ao1, aY, bY); MM(aX, bX); MM(aY, bY);               // t=79 (buf3)

    // ---- main log_cosh rowsums -> redsh ----
    // D 32x32: col = l31, row = (reg&3) + 8*(reg>>2) + 4*lh; f = col&7 = l&7
    {
        const float hbv = hidden_bias[l & 7];
#pragma unroll
        for (int mi = 0; mi < 4; ++mi)
#pragma unroll
            for (int reg = 0; reg < 16; ++reg) {
                float v = log_cosh_f(acc[mi][0][reg] + hbv)
                        + log_cosh_f(acc[mi][1][reg] + hbv);
                v += __shfl_xor(v, 1);  v += __shfl_xor(v, 2);
                v += __shfl_xor(v, 4);  v += __shfl_xor(v, 8);
                v += __shfl_xor(v, 16);
                if (l31 == 0)
                    redsh[(wm * 128 + mi * 32 + (reg & 3) + 8 * (reg >> 2)
                           + 4 * lh) * 5 + wn] = v;
            }
    }

    // ---- loop-correlator mini-GEMMs (K=128 per j2), drain style ----
#pragma unroll 1
    for (int j2 = 0; j2 < 2; ++j2) {
        ZACC();
        __syncthreads();
        const int kb = j2 * 128;
        STGA(CVb, KLOOP, kb,      0);     STGA(LWbb, KLOOP, kb,      8192);
        STGA(CVb, KLOOP, kb + 32, 16384); STGA(LWbb, KLOOP, kb + 32, 24576);
        STGA(CVb, KLOOP, kb + 64, 32768); STGA(LWbb, KLOOP, kb + 64, 40960);
        STGA(CVb, KLOOP, kb + 96, 49152); STGA(LWbb, KLOOP, kb + 96, 57344);
        __syncthreads();   // full drain: all chunks resident
#pragma unroll
        for (int tt = 0; tt < 4; ++tt) {
            RD(tt * 16384, ao0, aX, bX); MM(aX, bX);
            RD(tt * 16384, ao1, aY, bY); MM(aY, bY);
        }
        const float lbv = (j2 ? l1hb : l0hb)[l & 7];
#pragma unroll
        for (int mi = 0; mi < 4; ++mi)
#pragma unroll
            for (int reg = 0; reg < 16; ++reg) {
                float v = log_cosh_f(acc[mi][0][reg] + lbv)
                        + log_cosh_f(acc[mi][1][reg] + lbv);
                v += __shfl_xor(v, 1);  v += __shfl_xor(v, 2);
                v += __shfl_xor(v, 4);  v += __shfl_xor(v, 8);
                v += __shfl_xor(v, 16);
                if (l31 == 0)
                    redsh[(wm * 128 + mi * 32 + (reg & 3) + 8 * (reg >> 2)
                           + 4 * lh) * 5 + wn] += v;
            }
    }

    // ---- final cross-wave sum ----
    __syncthreads();
    if (tid < 256) {
        float t = redsh[tid * 5 + 0] + redsh[tid * 5 + 1] +
                  redsh[tid * 5 + 2] + redsh[tid * 5 + 3];
        partials[(size_t)nt * B_ + b0 + tid] = t;
    }
}

// ---------------------------------------------------------------------------
// Kernel 4: out[b] = initb[b] + sum over n-tiles
// ---------------------------------------------------------------------------
__global__ __launch_bounds__(256) void finalize_out(
    const float* __restrict__ initb, const float* __restrict__ partials,
    float* __restrict__ out)
{
    int b = blockIdx.x * 256 + threadIdx.x;
    float s = initb[b];
#pragma unroll
    for (int t = 0; t < NT2; ++t) s += partials[(size_t)t * B_ + b];
    out[b] = s;
}

extern "C" void kernel_launch(void* const* d_in, const int* in_sizes, int n_in,
                              void* d_out, int out_size, void* d_ws, size_t ws_size,
                              hipStream_t stream) {
    const float* x    = (const float*)d_in[0];
    const int* symm   = (const int*)d_in[1];
    const int* corr0  = (const int*)d_in[2];
    const int* corr1  = (const int*)d_in[3];
    const int* corr2  = (const int*)d_in[4];
    const int* corr3  = (const int*)d_in[5];
    const int* c0s    = (const int*)d_in[6];
    const int* c1s    = (const int*)d_in[7];
    const int* c2s    = (const int*)d_in[8];
    const int* c3s    = (const int*)d_in[9];
    const float* hb   = (const float*)d_in[10];
    const float* sk   = (const float*)d_in[11];
    const float* vb   = (const float*)d_in[12];
    const float* cb0  = (const float*)d_in[13];
    const float* ck0  = (const float*)d_in[14];
    const float* cb1  = (const float*)d_in[15];
    const float* ck1  = (const float*)d_in[16];
    const float* cb2  = (const float*)d_in[17];
    const float* ck2  = (const float*)d_in[18];
    const float* cb3  = (const float*)d_in[19];
    const float* ck3  = (const float*)d_in[20];
    const float* l0hb = (const float*)d_in[21];
    const float* l0k  = (const float*)d_in[22];
    const float* l1hb = (const float*)d_in[23];
    const float* l1k  = (const float*)d_in[24];

    ushort_t* wsu = (ushort_t*)d_ws;
    ushort_t* Wb  = wsu;                            // 4608*2560
    ushort_t* XA  = Wb + (size_t)NOUT * KPAD;       // 16384*2560
    ushort_t* LWb = XA + (size_t)B_ * KPAD;         // 4608*256
    ushort_t* CVL = LWb + (size_t)NOUT * KLOOP;     // 16384*256
    float* initb    = (float*)(CVL + (size_t)B_ * KLOOP);  // 16384
    float* partials = initb + B_;                          // 18*16384

    build_w<<<576, 256, 0, stream>>>(
        symm, c0s, c1s, c2s, c3s, sk, ck0, ck1, ck2, ck3, l0k, l1k, Wb, LWb);
    build_cv<<<B_, 256, 0, stream>>>(
        x, corr0, corr1, corr2, corr3, vb, cb0, cb1, cb2, cb3, XA, CVL, initb);
    mfma_gemm<<<1152, 512, 0, stream>>>(
        XA, Wb, CVL, LWb, hb, l0hb, l1hb, partials);
    finalize_out<<<B_ / 256, 256, 0, stream>>>(initb, partials, (float*)d_out);
}

// Round 9
// 670.198 us; speedup vs baseline: 1.1235x; 1.1235x over previous
//
#include <hip/hip_runtime.h>
#include <math.h>

#define B_    16384
#define N_    1152
#define KPAD  2496   // 1152 + 576 + 576 + 144 (cv23 3-slot) + 48 pad = 78 x 32
#define KLOOP 256    // per-j2: 72 slots + 56 pad -> 128, x2
#define NOUT  4608
#define NT    36     // NOUT/128
#define LOG2F_ 0.69314718055994530942f

typedef unsigned short ushort_t;
typedef __attribute__((ext_vector_type(8))) short short8;
typedef __attribute__((ext_vector_type(4))) float floatx4;

__device__ __forceinline__ float log_cosh_f(float t) {
    float a = fabsf(t);
    return a + __logf(1.0f + __expf(-2.0f * a)) - LOG2F_;
}
__device__ __forceinline__ ushort_t bf16_rne(float f) {
    unsigned int u = __float_as_uint(f);
    return (ushort_t)((u + 0x7fffu + ((u >> 16) & 1u)) >> 16);
}
__device__ __forceinline__ float bf16_to_f(ushort_t h) {
    return __uint_as_float(((unsigned int)h) << 16);
}

typedef __attribute__((address_space(1))) const unsigned int guint;
typedef __attribute__((address_space(3))) unsigned int luint;
__device__ __forceinline__ void gload16(const ushort_t* src, ushort_t* dst) {
    __builtin_amdgcn_global_load_lds((guint*)src, (luint*)dst, 16, 0, 0);
}

// ---------------------------------------------------------------------------
// Kernel 1: gather + transpose + bf16-encode weights.
// ---------------------------------------------------------------------------
__global__ __launch_bounds__(256) void build_w(
    const int* __restrict__ symm,
    const int* __restrict__ c0s, const int* __restrict__ c1s,
    const int* __restrict__ c2s, const int* __restrict__ c3s,
    const float* __restrict__ sk,
    const float* __restrict__ ck0, const float* __restrict__ ck1,
    const float* __restrict__ ck2, const float* __restrict__ ck3,
    const float* __restrict__ l0k, const float* __restrict__ l1k,
    ushort_t* __restrict__ Wb, ushort_t* __restrict__ LWb)
{
    __shared__ int idx[2352];
    const int s = blockIdx.x;
    const int tid = threadIdx.x;
    for (int i = tid; i < 1152; i += 256) idx[i] = symm[s * N_ + i];
    for (int i = tid; i < 576; i += 256) idx[1152 + i] = c0s[s * 576 + i];
    for (int i = tid; i < 576; i += 256) idx[1728 + i] = c1s[s * 576 + i];
    if (tid < 24) idx[2304 + tid] = c2s[s * 24 + tid];
    else if (tid < 48) idx[2328 + (tid - 24)] = c3s[s * 24 + (tid - 24)];
    __syncthreads();
    for (int f = 0; f < 8; ++f) {
        ushort_t* wr = Wb + (size_t)(s * 8 + f) * KPAD;
        for (int k = tid; k < KPAD; k += 256) {
            ushort_t o;
            if (k < 1152)      o = bf16_rne(sk[f * N_ + idx[k]]);
            else if (k < 1728) o = bf16_rne(ck0[f * 576 + idx[k]]);
            else if (k < 2304) o = bf16_rne(ck1[f * 576 + idx[k]]);
            else if (k < 2448) {
                int q = k - 2304, g = q / 48, c = q - g * 48;
                float w = (c < 24) ? ck2[f * 24 + idx[2304 + c]]
                                   : ck3[f * 24 + idx[2328 + (c - 24)]];
                ushort_t hi = bf16_rne(w);
                o = (g < 2) ? hi : bf16_rne(w - bf16_to_f(hi));
            } else o = 0;
            wr[k] = o;
        }
        ushort_t* lr = LWb + (size_t)(s * 8 + f) * KLOOP;
        for (int k2 = tid; k2 < KLOOP; k2 += 256) {
            int j2 = k2 >> 7, q = k2 & 127;
            ushort_t o = 0;
            if (q < 72) {
                int g = q / 24, c = q - g * 24;
                float w = j2 ? l1k[f * 24 + idx[2328 + c]]
                             : l0k[f * 24 + idx[2304 + c]];
                ushort_t hi = bf16_rne(w);
                o = (g < 2) ? hi : bf16_rne(w - bf16_to_f(hi));
            }
            lr[k2] = o;
        }
    }
}

// ---------------------------------------------------------------------------
// Kernel 2: augmented A matrix (bf16) + loop-cv matrix + scalar bias.
// ---------------------------------------------------------------------------
__global__ __launch_bounds__(256) void build_cv(
    const float* __restrict__ x,
    const int* __restrict__ corr0, const int* __restrict__ corr1,
    const int* __restrict__ corr2, const int* __restrict__ corr3,
    const float* __restrict__ vb,
    const float* __restrict__ cb0, const float* __restrict__ cb1,
    const float* __restrict__ cb2, const float* __restrict__ cb3,
    ushort_t* __restrict__ XA, ushort_t* __restrict__ CVL,
    float* __restrict__ initb)
{
    __shared__ float xs[N_];
    __shared__ float red[256];
    __shared__ float cvhi[48], cvlo[48];
    const int tid = threadIdx.x;
    const int b = blockIdx.x;
    ushort_t* xr = XA + (size_t)b * KPAD;

    float bias = 0.f;
    const float vb0 = vb[0], vb1 = vb[1];
    for (int i = tid; i < N_; i += 256) {
        float v = x[(size_t)b * N_ + i];
        xs[i] = v;
        bias += v * ((i & 1) ? vb1 : vb0);
        xr[i] = bf16_rne(v);
    }
    __syncthreads();
    float s0 = 0.f, s1 = 0.f, s2 = 0.f, s3 = 0.f;
    for (int c = tid; c < 576; c += 256) {
        const int* i0 = corr0 + c * 4;
        float p = xs[i0[0]] * xs[i0[1]] * xs[i0[2]] * xs[i0[3]];
        xr[1152 + c] = bf16_rne(p); s0 += p;
        const int* i1 = corr1 + c * 4;
        float q = xs[i1[0]] * xs[i1[1]] * xs[i1[2]] * xs[i1[3]];
        xr[1728 + c] = bf16_rne(q); s1 += q;
    }
    if (tid < 48) {
        int j2 = tid / 24, c = tid - j2 * 24;
        const int* ii = (j2 ? corr3 : corr2) + c * 24;
        float p = 1.f;
        for (int j = 0; j < 24; ++j) p *= xs[ii[j]];
        float hv = bf16_to_f(bf16_rne(p));
        cvhi[tid] = hv;
        cvlo[tid] = p - hv;
        if (j2) s3 = p; else s2 = p;
    }
    __syncthreads();
    for (int i = tid; i < KPAD - 2304; i += 256) {
        ushort_t o = 0;
        if (i < 144) {
            int g = i / 48, c = i - g * 48;
            o = bf16_rne(g == 1 ? cvlo[c] : cvhi[c]);
        }
        xr[2304 + i] = o;
    }
    ushort_t* cr = CVL + (size_t)b * KLOOP;
    for (int k2 = tid; k2 < KLOOP; k2 += 256) {
        int j2 = k2 >> 7, q = k2 & 127;
        ushort_t o = 0;
        if (q < 72) {
            int g = q / 24, c = q - g * 24;
            o = bf16_rne(g == 1 ? cvlo[j2 * 24 + c] : cvhi[j2 * 24 + c]);
        }
        cr[k2] = o;
    }
    bias += cb0[0] * s0 + cb1[0] * s1 + cb2[0] * s2 + cb3[0] * s3;
    red[tid] = bias;
    __syncthreads();
    for (int off = 128; off; off >>= 1) {
        if (tid < off) red[tid] += red[tid + off];
        __syncthreads();
    }
    if (tid == 0) initb[b] = red[0];
}

// ---------------------------------------------------------------------------
// Kernel 3: 128x128-tile MFMA GEMM, 4 waves (2M x 2N), wave 64x64, BK=32,
// FOUR 16KB LDS buffers, 2 blocks/CU. Register READ-AHEAD pipeline:
//   tile t: {RD frags(t+1) -> regs || STAGE(t+3)} ; sched_barrier ;
//           MFMA(t) from regs read LAST tile (compiler emits the partial
//           lgkmcnt(8) -> MFMA overlaps the 8 in-flight ds_reads) ;
//           vmcnt(4) ; s_barrier.
// vmcnt(4) proof: stage(t+1) issued at t-2; at barrier end-of(t-1) the only
// newer loads are stage(t+2)'s 4 -> vmcnt(4) forces stage(t+1) complete
// before RD at tile t. Overwrite: stage(t+3) hits the buffer whose reads
// (issued t-2) were consumed by MFMA(t-1) -> drained before its barrier.
// All LDS offsets compile-time immediates; global srcs = 4 persistent
// per-lane pointers bumped +128us per 4-tile unroll (VALU ~8/tile, was ~50).
// Swizzle: phys_oct = oct ^ ((row>>1)&3), both sides (R5-R7 verified, 0 conf).
// ---------------------------------------------------------------------------
__global__ __launch_bounds__(256, 2) void mfma_gemm(
    const ushort_t* __restrict__ XA, const ushort_t* __restrict__ Wb,
    const ushort_t* __restrict__ CVL, const ushort_t* __restrict__ LWb,
    const float* __restrict__ hidden_bias,
    const float* __restrict__ l0hb, const float* __restrict__ l1hb,
    float* __restrict__ partials)
{
    __shared__ __align__(16) ushort_t sh[32768];  // 4 bufs x (A 4096 | B 4096)
    __shared__ float redsh[384];                  // [128 rows][3]

    const int tid = threadIdx.x;
    const int l = tid & 63, w = tid >> 6;
    const int wm = w >> 1, wn = w & 1;            // 2M x 2N waves
    const int lrow = l & 15, lg = l >> 4;
    const int sgr = ((tid & 3) ^ ((tid >> 3) & 3)) * 8;   // stage src swizzle
    const int srow = tid >> 2;                    // 0..63
    const int wb512 = w * 512;                    // wave stage-dest base (us)

    // bijective XCD swizzle: 4608 blocks = 8 chunks x 576; bt-fastest so the
    // 0.64MB Wb panel of an nt stays L2-hot across 128 consecutive blocks
    const int bid = blockIdx.x;
    const int swz = (bid & 7) * 576 + (bid >> 3);
    const int nt = swz >> 7, bt = swz & 127;      // 36 x 128
    const int n0 = nt * 128, b0 = bt * 128;

    // persistent per-lane global sources
    const ushort_t* pA0 = XA + (size_t)(b0 + srow) * KPAD + sgr;
    const ushort_t* pA1 = pA0 + (size_t)64 * KPAD;
    const ushort_t* pB0 = Wb + (size_t)(n0 + srow) * KPAD + sgr;
    const ushort_t* pB1 = pB0 + (size_t)64 * KPAD;

    // frag read base addresses (ushort units; per-thread registers)
    const int oct = (lg ^ ((lrow >> 1) & 3)) * 8;
    const int aoff = (wm * 64 + lrow) * 32 + oct;          // A region
    const int boff = 4096 + (wn * 64 + lrow) * 32 + oct;   // B region

    floatx4 acc[4][4];
    short8 RA[8], RB[8];   // [0..3]=A frags, [4..7]=B frags

    auto STG = [&](int bufUS, int offUS) {   // stage one 128x32 A+B chunk pair
        gload16(pA0 + offUS, &sh[bufUS + 0    + wb512]);
        gload16(pA1 + offUS, &sh[bufUS + 2048 + wb512]);
        gload16(pB0 + offUS, &sh[bufUS + 4096 + wb512]);
        gload16(pB1 + offUS, &sh[bufUS + 6144 + wb512]);
    };
    auto RD = [&](int bufUS, short8* R) {
#pragma unroll
        for (int mi = 0; mi < 4; ++mi)
            R[mi] = *(const short8*)&sh[bufUS + aoff + mi * 512];
#pragma unroll
        for (int ni = 0; ni < 4; ++ni)
            R[4 + ni] = *(const short8*)&sh[bufUS + boff + ni * 512];
    };
    auto MM = [&](short8* R) {
        __builtin_amdgcn_s_setprio(1);
#pragma unroll
        for (int mi = 0; mi < 4; ++mi)
#pragma unroll
            for (int ni = 0; ni < 4; ++ni)
                acc[mi][ni] = __builtin_amdgcn_mfma_f32_16x16x32_bf16(
                    R[mi], R[4 + ni], acc[mi][ni], 0, 0, 0);
        __builtin_amdgcn_s_setprio(0);
    };
#define PIPE_BAR() do { asm volatile("s_waitcnt vmcnt(4)" ::: "memory"); \
    __builtin_amdgcn_s_barrier(); } while (0)

#pragma unroll
    for (int mi = 0; mi < 4; ++mi)
#pragma unroll
        for (int ni = 0; ni < 4; ++ni) acc[mi][ni] = (floatx4){0.f, 0.f, 0.f, 0.f};

    // ---- prologue: stage tiles 0,1,2 ----
    STG(0, 0); STG(8192, 32); STG(16384, 64);
    asm volatile("s_waitcnt vmcnt(8)" ::: "memory");
    __builtin_amdgcn_s_barrier();
    RD(0, RA);                                   // frags(0)

    // ---- main loop: 19 x 4 tiles (t = 0..75), read-ahead + stage-ahead-3 ----
#pragma unroll 1
    for (int m = 0; m < 19; ++m) {
        RD(8192, RB);  STG(24576, 96);           // rd t+1 | stage t+3
        __builtin_amdgcn_sched_barrier(0);
        MM(RA); PIPE_BAR();                      // mfma t
        RD(16384, RA); STG(0, 128);
        __builtin_amdgcn_sched_barrier(0);
        MM(RB); PIPE_BAR();
        RD(24576, RB); STG(8192, 160);
        __builtin_amdgcn_sched_barrier(0);
        MM(RA); PIPE_BAR();
        RD(0, RA);     STG(16384, 192);
        __builtin_amdgcn_sched_barrier(0);
        MM(RB); PIPE_BAR();
        pA0 += 128; pA1 += 128; pB0 += 128; pB1 += 128;
    }
    // ---- peel t=76,77 (frags(77) resident: last vmcnt(4) left only the
    //      garbage stage(78) outstanding) ----
    RD(8192, RB);
    __builtin_amdgcn_sched_barrier(0);
    MM(RA);                                      // t=76
    MM(RB);                                      // t=77

    // ---- main log_cosh rowsums -> redsh (D: row=lg*4+reg, col=lrow) ----
    {
        const float hbv = hidden_bias[l & 7];
#pragma unroll
        for (int mi = 0; mi < 4; ++mi)
#pragma unroll
            for (int reg = 0; reg < 4; ++reg) {
                float v = 0.f;
#pragma unroll
                for (int ni = 0; ni < 4; ++ni)
                    v += log_cosh_f(acc[mi][ni][reg] + hbv);
                v += __shfl_xor(v, 1); v += __shfl_xor(v, 2);
                v += __shfl_xor(v, 4); v += __shfl_xor(v, 8);
                if (lrow == 0)
                    redsh[(wm * 64 + mi * 16 + lg * 4 + reg) * 3 + wn] = v;
            }
    }

    // ---- loop-correlator mini-GEMMs (K=128 per j2), drain style ----
    const ushort_t* pC0 = CVL + (size_t)(b0 + srow) * KLOOP + sgr;
    const ushort_t* pC1 = pC0 + (size_t)64 * KLOOP;
    const ushort_t* pL0 = LWb + (size_t)(n0 + srow) * KLOOP + sgr;
    const ushort_t* pL1 = pL0 + (size_t)64 * KLOOP;
    auto STGm = [&](int bufUS, int offUS) {
        gload16(pC0 + offUS, &sh[bufUS + 0    + wb512]);
        gload16(pC1 + offUS, &sh[bufUS + 2048 + wb512]);
        gload16(pL0 + offUS, &sh[bufUS + 4096 + wb512]);
        gload16(pL1 + offUS, &sh[bufUS + 6144 + wb512]);
    };
#pragma unroll
    for (int j2 = 0; j2 < 2; ++j2) {
#pragma unroll
        for (int mi = 0; mi < 4; ++mi)
#pragma unroll
            for (int ni = 0; ni < 4; ++ni) acc[mi][ni] = (floatx4){0.f, 0.f, 0.f, 0.f};
        __syncthreads();                          // drains everything
        const int kb = j2 * 128;
        STGm(0, kb); STGm(8192, kb + 32); STGm(16384, kb + 64); STGm(24576, kb + 96);
        __syncthreads();                          // all chunks resident
        RD(0, RA);     MM(RA);
        RD(8192, RB);  MM(RB);
        RD(16384, RA); MM(RA);
        RD(24576, RB); MM(RB);
        const float lbv = (j2 ? l1hb : l0hb)[l & 7];
#pragma unroll
        for (int mi = 0; mi < 4; ++mi)
#pragma unroll
            for (int reg = 0; reg < 4; ++reg) {
                float v = 0.f;
#pragma unroll
                for (int ni = 0; ni < 4; ++ni)
                    v += log_cosh_f(acc[mi][ni][reg] + lbv);
                v += __shfl_xor(v, 1); v += __shfl_xor(v, 2);
                v += __shfl_xor(v, 4); v += __shfl_xor(v, 8);
                if (lrow == 0)
                    redsh[(wm * 64 + mi * 16 + lg * 4 + reg) * 3 + wn] += v;
            }
    }

    // ---- final cross-wave sum ----
    __syncthreads();
    if (tid < 128) {
        float t = redsh[tid * 3 + 0] + redsh[tid * 3 + 1];
        partials[(size_t)nt * B_ + b0 + tid] = t;
    }
#undef PIPE_BAR
}

// ---------------------------------------------------------------------------
// Kernel 4: out[b] = initb[b] + sum over n-tiles
// ---------------------------------------------------------------------------
__global__ __launch_bounds__(256) void finalize_out(
    const float* __restrict__ initb, const float* __restrict__ partials,
    float* __restrict__ out)
{
    int b = blockIdx.x * 256 + threadIdx.x;
    float s = initb[b];
#pragma unroll
    for (int t = 0; t < NT; ++t) s += partials[(size_t)t * B_ + b];
    out[b] = s;
}

extern "C" void kernel_launch(void* const* d_in, const int* in_sizes, int n_in,
                              void* d_out, int out_size, void* d_ws, size_t ws_size,
                              hipStream_t stream) {
    const float* x    = (const float*)d_in[0];
    const int* symm   = (const int*)d_in[1];
    const int* corr0  = (const int*)d_in[2];
    const int* corr1  = (const int*)d_in[3];
    const int* corr2  = (const int*)d_in[4];
    const int* corr3  = (const int*)d_in[5];
    const int* c0s    = (const int*)d_in[6];
    const int* c1s    = (const int*)d_in[7];
    const int* c2s    = (const int*)d_in[8];
    const int* c3s    = (const int*)d_in[9];
    const float* hb   = (const float*)d_in[10];
    const float* sk   = (const float*)d_in[11];
    const float* vb   = (const float*)d_in[12];
    const float* cb0  = (const float*)d_in[13];
    const float* ck0  = (const float*)d_in[14];
    const float* cb1  = (const float*)d_in[15];
    const float* ck1  = (const float*)d_in[16];
    const float* cb2  = (const float*)d_in[17];
    const float* ck2  = (const float*)d_in[18];
    const float* cb3  = (const float*)d_in[19];
    const float* ck3  = (const float*)d_in[20];
    const float* l0hb = (const float*)d_in[21];
    const float* l0k  = (const float*)d_in[22];
    const float* l1hb = (const float*)d_in[23];
    const float* l1k  = (const float*)d_in[24];

    ushort_t* wsu = (ushort_t*)d_ws;
    ushort_t* Wb  = wsu;                            // 4608*2496
    ushort_t* XA  = Wb + (size_t)NOUT * KPAD;       // 16384*2496
    ushort_t* LWb = XA + (size_t)B_ * KPAD;         // 4608*256
    ushort_t* CVL = LWb + (size_t)NOUT * KLOOP;     // 16384*256
    float* initb    = (float*)(CVL + (size_t)B_ * KLOOP);  // 16384
    float* partials = initb + B_;                          // 36*16384

    build_w<<<576, 256, 0, stream>>>(
        symm, c0s, c1s, c2s, c3s, sk, ck0, ck1, ck2, ck3, l0k, l1k, Wb, LWb);
    build_cv<<<B_, 256, 0, stream>>>(
        x, corr0, corr1, corr2, corr3, vb, cb0, cb1, cb2, cb3, XA, CVL, initb);
    mfma_gemm<<<4608, 256, 0, stream>>>(
        XA, Wb, CVL, LWb, hb, l0hb, l1hb, partials);
    finalize_out<<<B_ / 256, 256, 0, stream>>>(initb, partials, (float*)d_out);
}

// Round 10
// 625.225 us; speedup vs baseline: 1.2044x; 1.0719x over previous
//
#include <hip/hip_runtime.h>
#include <math.h>

#define B_    16384
#define N_    1152
#define KPAD  2496   // 1152 + 576 + 576 + 144 (cv23 3-slot) + 48 pad = 78 x 32
#define KLOOP 256    // per-j2: 72 slots + 56 pad -> 128, x2
#define NOUT  4608
#define NT    36     // NOUT/128
#define LOG2F_ 0.69314718055994530942f

typedef unsigned short ushort_t;
typedef __attribute__((ext_vector_type(8))) short short8;
typedef __attribute__((ext_vector_type(4))) float floatx4;

__device__ __forceinline__ float log_cosh_f(float t) {
    float a = fabsf(t);
    return a + __logf(1.0f + __expf(-2.0f * a)) - LOG2F_;
}
__device__ __forceinline__ ushort_t bf16_rne(float f) {
    unsigned int u = __float_as_uint(f);
    return (ushort_t)((u + 0x7fffu + ((u >> 16) & 1u)) >> 16);
}
__device__ __forceinline__ float bf16_to_f(ushort_t h) {
    return __uint_as_float(((unsigned int)h) << 16);
}

typedef __attribute__((address_space(1))) const unsigned int guint;
typedef __attribute__((address_space(3))) unsigned int luint;
__device__ __forceinline__ void gload16(const ushort_t* src, ushort_t* dst) {
    __builtin_amdgcn_global_load_lds((guint*)src, (luint*)dst, 16, 0, 0);
}

// ---------------------------------------------------------------------------
// Kernel 1: gather + transpose + bf16-encode weights.
// ---------------------------------------------------------------------------
__global__ __launch_bounds__(256) void build_w(
    const int* __restrict__ symm,
    const int* __restrict__ c0s, const int* __restrict__ c1s,
    const int* __restrict__ c2s, const int* __restrict__ c3s,
    const float* __restrict__ sk,
    const float* __restrict__ ck0, const float* __restrict__ ck1,
    const float* __restrict__ ck2, const float* __restrict__ ck3,
    const float* __restrict__ l0k, const float* __restrict__ l1k,
    ushort_t* __restrict__ Wb, ushort_t* __restrict__ LWb)
{
    __shared__ int idx[2352];
    const int s = blockIdx.x;
    const int tid = threadIdx.x;
    for (int i = tid; i < 1152; i += 256) idx[i] = symm[s * N_ + i];
    for (int i = tid; i < 576; i += 256) idx[1152 + i] = c0s[s * 576 + i];
    for (int i = tid; i < 576; i += 256) idx[1728 + i] = c1s[s * 576 + i];
    if (tid < 24) idx[2304 + tid] = c2s[s * 24 + tid];
    else if (tid < 48) idx[2328 + (tid - 24)] = c3s[s * 24 + (tid - 24)];
    __syncthreads();
    for (int f = 0; f < 8; ++f) {
        ushort_t* wr = Wb + (size_t)(s * 8 + f) * KPAD;
        for (int k = tid; k < KPAD; k += 256) {
            ushort_t o;
            if (k < 1152)      o = bf16_rne(sk[f * N_ + idx[k]]);
            else if (k < 1728) o = bf16_rne(ck0[f * 576 + idx[k]]);
            else if (k < 2304) o = bf16_rne(ck1[f * 576 + idx[k]]);
            else if (k < 2448) {
                int q = k - 2304, g = q / 48, c = q - g * 48;
                float w = (c < 24) ? ck2[f * 24 + idx[2304 + c]]
                                   : ck3[f * 24 + idx[2328 + (c - 24)]];
                ushort_t hi = bf16_rne(w);
                o = (g < 2) ? hi : bf16_rne(w - bf16_to_f(hi));
            } else o = 0;
            wr[k] = o;
        }
        ushort_t* lr = LWb + (size_t)(s * 8 + f) * KLOOP;
        for (int k2 = tid; k2 < KLOOP; k2 += 256) {
            int j2 = k2 >> 7, q = k2 & 127;
            ushort_t o = 0;
            if (q < 72) {
                int g = q / 24, c = q - g * 24;
                float w = j2 ? l1k[f * 24 + idx[2328 + c]]
                             : l0k[f * 24 + idx[2304 + c]];
                ushort_t hi = bf16_rne(w);
                o = (g < 2) ? hi : bf16_rne(w - bf16_to_f(hi));
            }
            lr[k2] = o;
        }
    }
}

// ---------------------------------------------------------------------------
// Kernel 2: augmented A matrix (bf16) + loop-cv matrix + scalar bias.
// ---------------------------------------------------------------------------
__global__ __launch_bounds__(256) void build_cv(
    const float* __restrict__ x,
    const int* __restrict__ corr0, const int* __restrict__ corr1,
    const int* __restrict__ corr2, const int* __restrict__ corr3,
    const float* __restrict__ vb,
    const float* __restrict__ cb0, const float* __restrict__ cb1,
    const float* __restrict__ cb2, const float* __restrict__ cb3,
    ushort_t* __restrict__ XA, ushort_t* __restrict__ CVL,
    float* __restrict__ initb)
{
    __shared__ float xs[N_];
    __shared__ float red[256];
    __shared__ float cvhi[48], cvlo[48];
    const int tid = threadIdx.x;
    const int b = blockIdx.x;
    ushort_t* xr = XA + (size_t)b * KPAD;

    float bias = 0.f;
    const float vb0 = vb[0], vb1 = vb[1];
    for (int i = tid; i < N_; i += 256) {
        float v = x[(size_t)b * N_ + i];
        xs[i] = v;
        bias += v * ((i & 1) ? vb1 : vb0);
        xr[i] = bf16_rne(v);
    }
    __syncthreads();
    float s0 = 0.f, s1 = 0.f, s2 = 0.f, s3 = 0.f;
    for (int c = tid; c < 576; c += 256) {
        const int* i0 = corr0 + c * 4;
        float p = xs[i0[0]] * xs[i0[1]] * xs[i0[2]] * xs[i0[3]];
        xr[1152 + c] = bf16_rne(p); s0 += p;
        const int* i1 = corr1 + c * 4;
        float q = xs[i1[0]] * xs[i1[1]] * xs[i1[2]] * xs[i1[3]];
        xr[1728 + c] = bf16_rne(q); s1 += q;
    }
    if (tid < 48) {
        int j2 = tid / 24, c = tid - j2 * 24;
        const int* ii = (j2 ? corr3 : corr2) + c * 24;
        float p = 1.f;
        for (int j = 0; j < 24; ++j) p *= xs[ii[j]];
        float hv = bf16_to_f(bf16_rne(p));
        cvhi[tid] = hv;
        cvlo[tid] = p - hv;
        if (j2) s3 = p; else s2 = p;
    }
    __syncthreads();
    for (int i = tid; i < KPAD - 2304; i += 256) {
        ushort_t o = 0;
        if (i < 144) {
            int g = i / 48, c = i - g * 48;
            o = bf16_rne(g == 1 ? cvlo[c] : cvhi[c]);
        }
        xr[2304 + i] = o;
    }
    ushort_t* cr = CVL + (size_t)b * KLOOP;
    for (int k2 = tid; k2 < KLOOP; k2 += 256) {
        int j2 = k2 >> 7, q = k2 & 127;
        ushort_t o = 0;
        if (q < 72) {
            int g = q / 24, c = q - g * 24;
            o = bf16_rne(g == 1 ? cvlo[j2 * 24 + c] : cvhi[j2 * 24 + c]);
        }
        cr[k2] = o;
    }
    bias += cb0[0] * s0 + cb1[0] * s1 + cb2[0] * s2 + cb3[0] * s3;
    red[tid] = bias;
    __syncthreads();
    for (int off = 128; off; off >>= 1) {
        if (tid < off) red[tid] += red[tid + off];
        __syncthreads();
    }
    if (tid == 0) initb[b] = red[0];
}

// ---------------------------------------------------------------------------
// Kernel 3: 256x128-tile MFMA GEMM, 4 waves (2M x 2N), WAVE TILE 128x64
// (0.375 ds_reads/MFMA vs round-9's 0.5 -> LDS-BW bound drops 25%), BK=32,
// THREE 24KB buffers (75KB total) -> 2 blocks/CU. Round-9 schedule kept:
//   tile t: vmcnt(6); s_barrier; STAGE(t+2); sched_barrier; 12 ds_reads;
//           32 MFMA (compiler partial-lgkmcnt interleaves).
// vmcnt(6): at tile-t barrier only stage(t+1)'s 6 gloads are newer, so
// stage(t) is complete. Write-safety: stage(t+2) targets buf[(t-1)%3] whose
// reads completed before each wave's last t-1 MFMA issued (operand dep),
// hence before the barrier. Swizzle: phys_oct = oct ^ ((row>>1)&3) both
// sides (R5/7/9-verified, 0 conflicts).
// ---------------------------------------------------------------------------
__global__ __launch_bounds__(256, 2) void mfma_gemm(
    const ushort_t* __restrict__ XA, const ushort_t* __restrict__ Wb,
    const ushort_t* __restrict__ CVL, const ushort_t* __restrict__ LWb,
    const float* __restrict__ hidden_bias,
    const float* __restrict__ l0hb, const float* __restrict__ l1hb,
    float* __restrict__ partials)
{
    __shared__ __align__(16) ushort_t sh[36864];  // 3 bufs x (A 8192 | B 4096)
    __shared__ float redsh[768];                  // [256 rows][3]

    const int tid = threadIdx.x;
    const int l = tid & 63, w = tid >> 6;
    const int wm = w >> 1, wn = w & 1;            // 2M x 2N waves
    const int lrow = l & 15, lg = l >> 4;
    const int srow = tid >> 2;                    // 0..63
    const int sgr = ((tid & 3) ^ ((srow >> 1) & 3)) * 8;  // stage src swizzle
    const int wb512 = w * 512;                    // wave stage-dest base (us)

    // bijective XCD swizzle: 2304 blocks = 8 chunks x 288, bt-fastest
    const int bid = blockIdx.x;
    const int swz = (bid & 7) * 288 + (bid >> 3);
    const int nt = swz >> 6, bt = swz & 63;       // 36 x 64
    const int n0 = nt * 128, b0 = bt * 256;

    // persistent per-lane global sources (A: 4 row-chunks, B: 2)
    const ushort_t* pa0 = XA + (size_t)(b0 + srow) * KPAD + sgr;
    const ushort_t* pa1 = pa0 + (size_t)64 * KPAD;
    const ushort_t* pa2 = pa0 + (size_t)128 * KPAD;
    const ushort_t* pa3 = pa0 + (size_t)192 * KPAD;
    const ushort_t* pb0 = Wb + (size_t)(n0 + srow) * KPAD + sgr;
    const ushort_t* pb1 = pb0 + (size_t)64 * KPAD;

    // frag read bases: A [256][32] at 0; B [128][32] at 8192 (us)
    const int oct = (lg ^ ((lrow >> 1) & 3)) * 8;
    const int aoff = (wm * 128 + lrow) * 32 + oct;
    const int boff = 8192 + (wn * 64 + lrow) * 32 + oct;

    floatx4 acc[8][4];

    auto STAGE = [&](int buf, int off) {   // one 256x32 A + 128x32 B tile
        gload16(pa0 + off, &sh[buf + 0    + wb512]);
        gload16(pa1 + off, &sh[buf + 2048 + wb512]);
        gload16(pa2 + off, &sh[buf + 4096 + wb512]);
        gload16(pa3 + off, &sh[buf + 6144 + wb512]);
        gload16(pb0 + off, &sh[buf + 8192 + wb512]);
        gload16(pb1 + off, &sh[buf + 10240 + wb512]);
    };
    auto TILE = [&](int buf) {
        short8 af[8], bf[4];
#pragma unroll
        for (int mi = 0; mi < 8; ++mi)
            af[mi] = *(const short8*)&sh[buf + aoff + mi * 512];
#pragma unroll
        for (int ni = 0; ni < 4; ++ni)
            bf[ni] = *(const short8*)&sh[buf + boff + ni * 512];
        __builtin_amdgcn_s_setprio(1);
#pragma unroll
        for (int mi = 0; mi < 8; ++mi)
#pragma unroll
            for (int ni = 0; ni < 4; ++ni)
                acc[mi][ni] = __builtin_amdgcn_mfma_f32_16x16x32_bf16(
                    af[mi], bf[ni], acc[mi][ni], 0, 0, 0);
        __builtin_amdgcn_s_setprio(0);
    };
#define VMB(N) do { asm volatile("s_waitcnt vmcnt(" #N ")" ::: "memory"); \
    __builtin_amdgcn_s_barrier(); } while (0)
#define SB0() __builtin_amdgcn_sched_barrier(0)

#pragma unroll
    for (int mi = 0; mi < 8; ++mi)
#pragma unroll
        for (int ni = 0; ni < 4; ++ni) acc[mi][ni] = (floatx4){0.f, 0.f, 0.f, 0.f};

    // ---- prologue: stage tiles 0,1 ----
    STAGE(0, 0); STAGE(12288, 32);

    // ---- main loop: 78 tiles = 25 x 3 + peel(75,76,77); base bumps 96/iter
#pragma unroll 1
    for (int m = 0; m < 25; ++m) {
        VMB(6); STAGE(24576, 64);  SB0(); TILE(0);       // t=3m,   stage 3m+2
        VMB(6); STAGE(0, 96);      SB0(); TILE(12288);   // t=3m+1, stage 3m+3
        VMB(6); STAGE(12288, 128); SB0(); TILE(24576);   // t=3m+2, stage 3m+4
        pa0 += 96; pa1 += 96; pa2 += 96; pa3 += 96; pb0 += 96; pb1 += 96;
    }
    VMB(6); STAGE(24576, 64); SB0(); TILE(0);            // t=75, stage 77
    VMB(6); TILE(12288);                                 // t=76
    VMB(0); TILE(24576);                                 // t=77

    // ---- main log_cosh rowsums -> redsh (D: row=lg*4+reg, col=lrow) ----
    {
        const float hbv = hidden_bias[l & 7];
#pragma unroll
        for (int mi = 0; mi < 8; ++mi)
#pragma unroll
            for (int reg = 0; reg < 4; ++reg) {
                float v = 0.f;
#pragma unroll
                for (int ni = 0; ni < 4; ++ni)
                    v += log_cosh_f(acc[mi][ni][reg] + hbv);
                v += __shfl_xor(v, 1); v += __shfl_xor(v, 2);
                v += __shfl_xor(v, 4); v += __shfl_xor(v, 8);
                if (lrow == 0)
                    redsh[(wm * 128 + mi * 16 + lg * 4 + reg) * 3 + wn] = v;
            }
    }

    // ---- loop-correlator mini-GEMMs (K=128 per j2), drain style ----
    const ushort_t* pc0 = CVL + (size_t)(b0 + srow) * KLOOP + sgr;
    const ushort_t* pc1 = pc0 + (size_t)64 * KLOOP;
    const ushort_t* pc2 = pc0 + (size_t)128 * KLOOP;
    const ushort_t* pc3 = pc0 + (size_t)192 * KLOOP;
    const ushort_t* pl0 = LWb + (size_t)(n0 + srow) * KLOOP + sgr;
    const ushort_t* pl1 = pl0 + (size_t)64 * KLOOP;
    auto STGm = [&](int buf, int off) {
        gload16(pc0 + off, &sh[buf + 0    + wb512]);
        gload16(pc1 + off, &sh[buf + 2048 + wb512]);
        gload16(pc2 + off, &sh[buf + 4096 + wb512]);
        gload16(pc3 + off, &sh[buf + 6144 + wb512]);
        gload16(pl0 + off, &sh[buf + 8192 + wb512]);
        gload16(pl1 + off, &sh[buf + 10240 + wb512]);
    };
#pragma unroll
    for (int j2 = 0; j2 < 2; ++j2) {
#pragma unroll
        for (int mi = 0; mi < 8; ++mi)
#pragma unroll
            for (int ni = 0; ni < 4; ++ni) acc[mi][ni] = (floatx4){0.f, 0.f, 0.f, 0.f};
        __syncthreads();                          // drains all reads+loads
        const int kb = j2 * 128;
        STGm(0, kb); STGm(12288, kb + 32); STGm(24576, kb + 64);
        __syncthreads();                          // k0..k2 resident
        TILE(0); TILE(12288);
        __syncthreads();                          // buf0 reads complete
        STGm(0, kb + 96);
        __syncthreads();                          // k3 resident
        TILE(24576); TILE(0);
        const float lbv = (j2 ? l1hb : l0hb)[l & 7];
#pragma unroll
        for (int mi = 0; mi < 8; ++mi)
#pragma unroll
            for (int reg = 0; reg < 4; ++reg) {
                float v = 0.f;
#pragma unroll
                for (int ni = 0; ni < 4; ++ni)
                    v += log_cosh_f(acc[mi][ni][reg] + lbv);
                v += __shfl_xor(v, 1); v += __shfl_xor(v, 2);
                v += __shfl_xor(v, 4); v += __shfl_xor(v, 8);
                if (lrow == 0)
                    redsh[(wm * 128 + mi * 16 + lg * 4 + reg) * 3 + wn] += v;
            }
    }

    // ---- final cross-wave sum (256 rows, wn in {0,1}) ----
    __syncthreads();
    {
        float t = redsh[tid * 3 + 0] + redsh[tid * 3 + 1];
        partials[(size_t)nt * B_ + b0 + tid] = t;
    }
#undef VMB
#undef SB0
}

// ---------------------------------------------------------------------------
// Kernel 4: out[b] = initb[b] + sum over n-tiles
// ---------------------------------------------------------------------------
__global__ __launch_bounds__(256) void finalize_out(
    const float* __restrict__ initb, const float* __restrict__ partials,
    float* __restrict__ out)
{
    int b = blockIdx.x * 256 + threadIdx.x;
    float s = initb[b];
#pragma unroll
    for (int t = 0; t < NT; ++t) s += partials[(size_t)t * B_ + b];
    out[b] = s;
}

extern "C" void kernel_launch(void* const* d_in, const int* in_sizes, int n_in,
                              void* d_out, int out_size, void* d_ws, size_t ws_size,
                              hipStream_t stream) {
    const float* x    = (const float*)d_in[0];
    const int* symm   = (const int*)d_in[1];
    const int* corr0  = (const int*)d_in[2];
    const int* corr1  = (const int*)d_in[3];
    const int* corr2  = (const int*)d_in[4];
    const int* corr3  = (const int*)d_in[5];
    const int* c0s    = (const int*)d_in[6];
    const int* c1s    = (const int*)d_in[7];
    const int* c2s    = (const int*)d_in[8];
    const int* c3s    = (const int*)d_in[9];
    const float* hb   = (const float*)d_in[10];
    const float* sk   = (const float*)d_in[11];
    const float* vb   = (const float*)d_in[12];
    const float* cb0  = (const float*)d_in[13];
    const float* ck0  = (const float*)d_in[14];
    const float* cb1  = (const float*)d_in[15];
    const float* ck1  = (const float*)d_in[16];
    const float* cb2  = (const float*)d_in[17];
    const float* ck2  = (const float*)d_in[18];
    const float* cb3  = (const float*)d_in[19];
    const float* ck3  = (const float*)d_in[20];
    const float* l0hb = (const float*)d_in[21];
    const float* l0k  = (const float*)d_in[22];
    const float* l1hb = (const float*)d_in[23];
    const float* l1k  = (const float*)d_in[24];

    ushort_t* wsu = (ushort_t*)d_ws;
    ushort_t* Wb  = wsu;                            // 4608*2496
    ushort_t* XA  = Wb + (size_t)NOUT * KPAD;       // 16384*2496
    ushort_t* LWb = XA + (size_t)B_ * KPAD;         // 4608*256
    ushort_t* CVL = LWb + (size_t)NOUT * KLOOP;     // 16384*256
    float* initb    = (float*)(CVL + (size_t)B_ * KLOOP);  // 16384
    float* partials = initb + B_;                          // 36*16384

    build_w<<<576, 256, 0, stream>>>(
        symm, c0s, c1s, c2s, c3s, sk, ck0, ck1, ck2, ck3, l0k, l1k, Wb, LWb);
    build_cv<<<B_, 256, 0, stream>>>(
        x, corr0, corr1, corr2, corr3, vb, cb0, cb1, cb2, cb3, XA, CVL, initb);
    mfma_gemm<<<2304, 256, 0, stream>>>(
        XA, Wb, CVL, LWb, hb, l0hb, l1hb, partials);
    finalize_out<<<B_ / 256, 256, 0, stream>>>(initb, partials, (float*)d_out);
}